// Round 15
// baseline (179.887 us; speedup 1.0000x reference)
//
#include <hip/hip_runtime.h>
#include <math.h>

// ---------------------------------------------------------------------------
// PINN beam loss via forward-mode bivariate jets (v15: LDS-pipe relief).
// Jet of f(z + t*(1,1) + s*(1,0)):  y[k]=coeff t^k, z[k]=coeff t^k s.
// Layer-1: pre-act = p0 + d*t + wx*s  =>  z[k] = (k+1)*(wx/d)*y[k+1] exactly.
//
// v14 post-mortem: per-CU LDS data pipe ~84% saturated (180 ds_read_b128 +
// 144 ds_write_b32 per wave) while MfmaUtil 21 / VALUBusy 46 -> LDS-bound.
// v15: 2 waves x 4 M-tiles (was 4 x 2) -> each B fragment feeds 4 MFMAs,
// halving per-block B reads; jet writes packed b64; single buffer.
// VGPR control: layer-2 activations packed to fp16 uint2 immediately
// (acc[4][NC] freed before layer-3), peak live ~200 under the 256 cap.
// MFMA mapping identical to v13 (verified absmax 2.4e-4).
// ---------------------------------------------------------------------------

typedef _Float16 half8 __attribute__((ext_vector_type(8)));
typedef float f32x4 __attribute__((ext_vector_type(4)));

#define W2T_HOFF 32768     // half-offset of W2t[128][512] in ws (byte 65536)
#define W3T_HOFF 98304     // half-offset of W3t[64][128]  in ws (byte 196608)

__device__ __forceinline__ unsigned int pkrtz(float lo, float hi) {
    return __builtin_bit_cast(unsigned int, __builtin_amdgcn_cvt_pkrtz(lo, hi));
}

__device__ __forceinline__ float fast_tanh(float x) {
    float ax = fabsf(x);
    float e  = __expf(-2.0f * ax);
    float y  = (1.0f - e) * __builtin_amdgcn_rcpf(1.0f + e);
    return copysignf(y, x);
}

template<int NA, int NB>
__device__ __forceinline__ void tanh_jet(const float (&p)[NA], const float (&q)[NB],
                                         float (&y)[NA], float (&r)[NB]) {
    constexpr int NU = ((NA - 1) > NB ? (NA - 1) : NB);
    float u[NU];
    y[0] = fast_tanh(p[0]);
    u[0] = fmaf(-y[0], y[0], 1.0f);
    if constexpr (NA >= 2) y[1] = u[0] * p[1];
    if constexpr (NU >= 2) u[1] = -2.0f * y[0] * y[1];
    if constexpr (NA >= 3) y[2] = fmaf(u[0], p[2], 0.5f * u[1] * p[1]);
    if constexpr (NU >= 3) u[2] = -fmaf(2.0f * y[0], y[2], y[1] * y[1]);
    if constexpr (NA >= 4) y[3] = fmaf(u[0], p[3], fmaf((2.0f/3.0f) * u[1], p[2],
                                       (1.0f/3.0f) * u[2] * p[1]));
    if constexpr (NU >= 4) u[3] = -2.0f * fmaf(y[0], y[3], y[1] * y[2]);
    if constexpr (NA >= 5) y[4] = fmaf(u[0], p[4], fmaf(0.75f * u[1], p[3],
                                       fmaf(0.5f * u[2], p[2], 0.25f * u[3] * p[1])));
    #pragma unroll
    for (int k = 0; k < NB; ++k) {
        float s = 0.0f;
        #pragma unroll
        for (int j = 0; j <= k; ++j) s = fmaf(u[j], q[k - j], s);
        r[k] = s;
    }
}

// layer-1 jet of neuron nn, interleaved [y0,z0,y1,z1,...,y_{NB-1},z_{NB-1},y_{NA-1}]
template<int NA, int NB, int NC>
__device__ __forceinline__ void l1jet(int nn, float x_in, float a_in,
                                      const float* __restrict__ W1,
                                      const float* __restrict__ b1,
                                      float (&jt)[NC]) {
    const float wx = W1[nn];
    const float wa = W1[512 + nn];
    float d = wx + wa;
    if (d == 0.0f) d = 1e-30f;
    const float p0 = fmaf(wx, x_in, fmaf(wa, a_in, b1[nn]));
    const float y0 = fast_tanh(p0);
    const float u0 = fmaf(-y0, y0, 1.0f);
    const float e  = wx * __builtin_amdgcn_rcpf(d);
    float y1 = 0.0f, y2 = 0.0f, y3 = 0.0f, y4 = 0.0f;
    if constexpr (NA >= 2) y1 = u0 * d;
    if constexpr (NA >= 3) { const float u1 = -2.0f * y0 * y1; y2 = 0.5f * u1 * d; }
    if constexpr (NA >= 4) { const float u2 = -fmaf(2.0f * y0, y2, y1 * y1);
                             y3 = (1.0f/3.0f) * u2 * d; }
    if constexpr (NA >= 5) { const float u3 = -2.0f * fmaf(y0, y3, y1 * y2);
                             y4 = 0.25f * u3 * d; }
    jt[0] = y0;
    jt[1] = e * y1;
    if constexpr (NB >= 2) { jt[2] = y1; jt[3] = 2.0f * e * y2; }
    if constexpr (NB >= 3) { jt[4] = y2; jt[5] = 3.0f * e * y3; }
    if constexpr (NB >= 4) { jt[6] = y3; jt[7] = 4.0f * e * y4; }
    if constexpr (NA == 2) jt[2 * NB] = y1;
    else if constexpr (NA == 3) jt[2 * NB] = y2;
    else if constexpr (NA == 4) jt[2 * NB] = y3;
    else                        jt[2 * NB] = y4;
}

// Transpose + fp16-convert the weights: W2t[n][k] = W2[k][n], W3t[n][k] = W3[k][n]
__global__ __launch_bounds__(256)
void pinn_prep(const float* __restrict__ W2, const float* __restrict__ W3,
               _Float16* __restrict__ wsh)
{
    const int i = blockIdx.x * 256 + threadIdx.x;
    if (i < 65536) {
        const int n = i >> 9, k = i & 511;
        wsh[W2T_HOFF + i] = (_Float16)W2[k * 128 + n];
    }
    if (i < 8192) {
        const int n = i >> 7, k = i & 127;
        wsh[W3T_HOFF + i] = (_Float16)W3[k * 64 + n];
    }
}

template<int NA, int NB, int TYPE>
__device__ __forceinline__ void eval_body(
    int bi, const float* __restrict__ inp,
    const float* __restrict__ W1, const float* __restrict__ b1,
    const _Float16* __restrict__ W2t, const float* __restrict__ b2,
    const _Float16* __restrict__ W3t, const float* __restrict__ b3,
    const float* __restrict__ W4, const float* __restrict__ b4,
    float* __restrict__ ws, int N, int nbx,
    _Float16* __restrict__ hbuf, float (*red)[16][9])
{
    constexpr int NC = NA + NB;              // 9 / 7 / 3 jet components

    const int t    = threadIdx.x;            // 0..127
    const int l    = t & 63;
    const int w    = t >> 6;                 // wave 0..1
    const int col  = l & 15;                 // MFMA N-col = sample
    const int rgrp = l >> 4;                 // 0..3
    const int kb   = rgrp * 8;               // fragment k base (contiguous 8)

    // layer-1 production mapping: sample = t&15, k-local base = (t>>4)*8
    const int s1   = t & 15;
    const int klb  = (t >> 4) * 8;           // 0..56, 8 jets/thread/chunk
    const int i1   = bi * 16 + s1;
    const int ii   = (i1 < N) ? i1 : (N - 1);
    const float a1 = inp[2 * ii + 1];
    float x1;
    if constexpr (TYPE == 0)      x1 = inp[2 * ii + 0];
    else if constexpr (TYPE == 1) x1 = 0.0f;
    else                          x1 = 1.0f;

    unsigned int* hb32 = reinterpret_cast<unsigned int*>(hbuf);

    // ---------------- layers 1+2 fused: 8 K-chunks of 64 ----------------
    f32x4 acc[4][NC];
    #pragma unroll
    for (int T = 0; T < 4; ++T)
        #pragma unroll
        for (int c = 0; c < NC; ++c) acc[T][c] = (f32x4)0.0f;

    const _Float16* Ab = W2t + (w * 64 + col) * 512;   // + T*16*512 + kg

    for (int ch = 0; ch < 8; ++ch) {
        // ---- layer 1: 8 jets/thread -> packed fp16 pairs, b64 writes ----
        #pragma unroll
        for (int hf = 0; hf < 2; ++hf) {
            float j0[NC], j1[NC], j2[NC], j3[NC];
            const int kn = ch * 64 + klb + 4 * hf;
            l1jet<NA, NB, NC>(kn + 0, x1, a1, W1, b1, j0);
            l1jet<NA, NB, NC>(kn + 1, x1, a1, W1, b1, j1);
            l1jet<NA, NB, NC>(kn + 2, x1, a1, W1, b1, j2);
            l1jet<NA, NB, NC>(kn + 3, x1, a1, W1, b1, j3);
            #pragma unroll
            for (int c = 0; c < NC; ++c) {
                uint2 v;
                v.x = pkrtz(j0[c], j1[c]);
                v.y = pkrtz(j2[c], j3[c]);
                *reinterpret_cast<uint2*>(
                    hb32 + (c * 16 + s1) * 36 + (klb >> 1) + 2 * hf) = v;
            }
        }
        __syncthreads();

        // ---- layer 2: 2 K-steps x NC comps, 4 row-tiles per wave ----
        #pragma unroll
        for (int ks = 0; ks < 2; ++ks) {
            const int kg = ch * 64 + ks * 32 + kb;
            half8 A[4];
            #pragma unroll
            for (int T = 0; T < 4; ++T)
                A[T] = *reinterpret_cast<const half8*>(Ab + T * 16 * 512 + kg);
            #pragma unroll
            for (int c = 0; c < NC; ++c) {
                const half8 B = *reinterpret_cast<const half8*>(
                    hbuf + (c * 16 + col) * 72 + ks * 32 + kb);
                #pragma unroll
                for (int T = 0; T < 4; ++T)
                    acc[T][c] = __builtin_amdgcn_mfma_f32_16x16x32_f16(A[T], B, acc[T][c], 0, 0, 0);
            }
        }
        __syncthreads();
    }

    // ------- layer-2 activation, packed to fp16 immediately (frees acc) ----
    // lane holds n2 = w*64 + T*16 + rgrp*4 + r, sample = col.
    uint2 h2p[4][NC];
    #pragma unroll
    for (int T = 0; T < 4; ++T) {
        float vv[NC][4];
        const float* b2p = b2 + w * 64 + T * 16 + rgrp * 4;
        #pragma unroll
        for (int r = 0; r < 4; ++r) {
            float pj[NA], qj[NB], yj[NA], rj[NB];
            #pragma unroll
            for (int j = 0; j < NA; ++j) pj[j] = acc[T][2 * j][r];
            #pragma unroll
            for (int j = 0; j < NB; ++j) qj[j] = acc[T][2 * j + 1][r];
            pj[0] += b2p[r];
            tanh_jet<NA, NB>(pj, qj, yj, rj);
            #pragma unroll
            for (int j = 0; j < NA; ++j) vv[2 * j][r] = yj[j];
            #pragma unroll
            for (int j = 0; j < NB; ++j) vv[2 * j + 1][r] = rj[j];
        }
        #pragma unroll
        for (int c = 0; c < NC; ++c) {
            h2p[T][c].x = pkrtz(vv[c][0], vv[c][1]);
            h2p[T][c].y = pkrtz(vv[c][2], vv[c][3]);
        }
    }

    // ---------------- layer 3: two store/mfma passes over K=128 ------------
    f32x4 acc3[2][NC];
    #pragma unroll
    for (int U = 0; U < 2; ++U)
        #pragma unroll
        for (int c = 0; c < NC; ++c) acc3[U][c] = (f32x4)0.0f;
    const _Float16* A3b = W3t + (w * 32 + col) * 128;  // + U*16*128 + kg

    #pragma unroll
    for (int pass = 0; pass < 2; ++pass) {
        __syncthreads();                     // prior jet-buffer reads complete
        if (w == pass) {                     // wave owning rows [64p,64p+64)
            #pragma unroll
            for (int T = 0; T < 4; ++T)
                #pragma unroll
                for (int c = 0; c < NC; ++c)
                    *reinterpret_cast<uint2*>(
                        hb32 + (c * 16 + col) * 36 + T * 8 + rgrp * 2) = h2p[T][c];
        }
        __syncthreads();
        #pragma unroll
        for (int ks = 0; ks < 2; ++ks) {
            const int kg = pass * 64 + ks * 32 + kb;
            half8 A3[2];
            #pragma unroll
            for (int U = 0; U < 2; ++U)
                A3[U] = *reinterpret_cast<const half8*>(A3b + U * 16 * 128 + kg);
            #pragma unroll
            for (int c = 0; c < NC; ++c) {
                const half8 B = *reinterpret_cast<const half8*>(
                    hbuf + (c * 16 + col) * 72 + ks * 32 + kb);
                #pragma unroll
                for (int U = 0; U < 2; ++U)
                    acc3[U][c] = __builtin_amdgcn_mfma_f32_16x16x32_f16(A3[U], B, acc3[U][c], 0, 0, 0);
            }
        }
    }

    // ---------------- layer 4 + loss ----------------
    // lane holds n3 = w*32 + U*16 + rgrp*4 + r, sample = col.
    float part[NC];
    #pragma unroll
    for (int c = 0; c < NC; ++c) part[c] = 0.0f;
    #pragma unroll
    for (int U = 0; U < 2; ++U) {
        const float* b3p = b3 + w * 32 + U * 16 + rgrp * 4;
        const float* w4p = W4 + w * 32 + U * 16 + rgrp * 4;
        #pragma unroll
        for (int r = 0; r < 4; ++r) {
            float pj[NA], qj[NB], yj[NA], rj[NB];
            #pragma unroll
            for (int j = 0; j < NA; ++j) pj[j] = acc3[U][2 * j][r];
            #pragma unroll
            for (int j = 0; j < NB; ++j) qj[j] = acc3[U][2 * j + 1][r];
            pj[0] += b3p[r];
            tanh_jet<NA, NB>(pj, qj, yj, rj);
            const float w4 = w4p[r];
            #pragma unroll
            for (int c = 0; c < NA; ++c) part[c] = fmaf(w4, yj[c], part[c]);
            #pragma unroll
            for (int c = 0; c < NB; ++c) part[NA + c] = fmaf(w4, rj[c], part[NA + c]);
        }
    }
    // reduce over the 4 row-groups of the wave
    #pragma unroll
    for (int c = 0; c < NC; ++c) {
        part[c] += __shfl_xor(part[c], 16, 64);
        part[c] += __shfl_xor(part[c], 32, 64);
    }
    if (l < 16) {
        #pragma unroll
        for (int c = 0; c < NC; ++c) red[w][l][c] = part[c];
    }
    __syncthreads();

    if (t < 16) {
        float pp[NC];
        #pragma unroll
        for (int c = 0; c < NC; ++c)
            pp[c] = red[0][t][c] + red[1][t][c];
        const int is = bi * 16 + t;
        const bool valid = (is < N);
        const float a_s = inp[2 * ((is < N) ? is : (N - 1)) + 1];
        const float A0v = pp[0] + b4[0];
        float t0 = 0.0f, t1 = 0.0f, t2 = 0.0f;
        constexpr float CC = 1.0f;   // P/(E*I)
        if constexpr (TYPE == 0) {
            const float gx = 6.0f * pp[NA + 3];
            const float ga = 24.0f * pp[4] - gx;
            t0 = (gx + CC) * (gx + CC) + (ga + CC) * (ga + CC);
        }
        if constexpr (TYPE == 1) {
            t0 = A0v * A0v;
            const float gx = pp[NA + 0];
            const float ga = pp[1] - gx;
            t1 = gx * gx + ga * ga;
        }
        if constexpr (TYPE == 2) {
            const float wa = a_s * A0v;
            t0 = wa * wa;
            const float g2x = pp[NA + 1];
            const float g2a = 2.0f * pp[2] - g2x;
            t1 = g2x * g2x + g2a * g2a;
            const float g3x = 2.0f * pp[NA + 2];
            const float g3a = 6.0f * pp[3] - g3x;
            const float om = 1.0f - a_s;
            t2 = om * om * (g3x * g3x + g3a * g3a);
        }
        if (!valid) { t0 = 0.0f; t1 = 0.0f; t2 = 0.0f; }
        #pragma unroll
        for (int m = 1; m <= 8; m <<= 1) {
            t0 += __shfl_xor(t0, m, 64);
            if constexpr (TYPE != 0) t1 += __shfl_xor(t1, m, 64);
            if constexpr (TYPE == 2) t2 += __shfl_xor(t2, m, 64);
        }
        if (t == 0) {
            if constexpr (TYPE == 0) {
                ws[bi] = t0;
            } else if constexpr (TYPE == 1) {
                ws[nbx + bi]     = t0;
                ws[2 * nbx + bi] = t1;
            } else {
                ws[3 * nbx + bi] = t0;
                ws[4 * nbx + bi] = t1;
                ws[5 * nbx + bi] = t2;
            }
        }
    }
}

__global__ __launch_bounds__(128, 2)
void pinn_fat(const float* __restrict__ inp,
              const float* __restrict__ W1, const float* __restrict__ b1,
              const _Float16* __restrict__ W2t, const float* __restrict__ b2,
              const _Float16* __restrict__ W3t, const float* __restrict__ b3,
              const float* __restrict__ W4, const float* __restrict__ b4,
              float* __restrict__ ws, int N, int nbx)
{
    __shared__ __align__(16) _Float16 hbuf[10368];   // [9][16][72] = 20736 B
    __shared__ float red[2][16][9];                  // 1152 B
    const int b = blockIdx.x;
    if (b < nbx)
        eval_body<5, 4, 0>(b, inp, W1, b1, W2t, b2, W3t, b3, W4, b4, ws, N, nbx, hbuf, red);
    else if (b < 2 * nbx)
        eval_body<4, 3, 2>(b - nbx, inp, W1, b1, W2t, b2, W3t, b3, W4, b4, ws, N, nbx, hbuf, red);
    else
        eval_body<2, 1, 1>(b - 2 * nbx, inp, W1, b1, W2t, b2, W3t, b3, W4, b4, ws, N, nbx, hbuf, red);
}

__global__ __launch_bounds__(1024)
void pinn_reduce(const float* __restrict__ ws, float* __restrict__ out,
                 int G, float invN, float inv2N)
{
    __shared__ float sh[16 * 6];
    float s[6];
    #pragma unroll
    for (int q = 0; q < 6; ++q) {
        float acc = 0.0f;
        for (int i = threadIdx.x; i < G; i += 1024) acc += ws[q * G + i];
        #pragma unroll
        for (int m = 1; m <= 32; m <<= 1) acc += __shfl_xor(acc, m, 64);
        s[q] = acc;
    }
    const int wid = threadIdx.x >> 6;
    if ((threadIdx.x & 63) == 0) {
        #pragma unroll
        for (int q = 0; q < 6; ++q) sh[wid * 6 + q] = s[q];
    }
    __syncthreads();
    if (threadIdx.x == 0) {
        float r[6];
        #pragma unroll
        for (int q = 0; q < 6; ++q) {
            float acc = 0.0f;
            for (int w = 0; w < 16; ++w) acc += sh[w * 6 + q];
            r[q] = acc;
        }
        const float pde   = r[0] * inv2N;
        const float w0    = r[1] * invN;
        const float w0x   = r[2] * inv2N;
        const float wL    = r[3] * invN;
        const float wLxx  = r[4] * inv2N;
        const float wLxxx = r[5] * inv2N;
        out[0] = pde + w0 + w0x + wL + wLxx + wLxxx;
        out[1] = pde;
        out[2] = w0;
        out[3] = w0x;
        out[4] = wL;
        out[5] = wLxx;
        out[6] = wLxxx;
    }
}

extern "C" void kernel_launch(void* const* d_in, const int* in_sizes, int n_in,
                              void* d_out, int out_size, void* d_ws, size_t ws_size,
                              hipStream_t stream) {
    const float* inp = (const float*)d_in[0];
    const float* W1  = (const float*)d_in[1];
    const float* b1  = (const float*)d_in[2];
    const float* W2  = (const float*)d_in[3];
    const float* b2  = (const float*)d_in[4];
    const float* W3  = (const float*)d_in[5];
    const float* b3  = (const float*)d_in[6];
    const float* W4  = (const float*)d_in[7];
    const float* b4  = (const float*)d_in[8];
    float* ws  = (float*)d_ws;
    _Float16* wsh = (_Float16*)d_ws;
    float* out = (float*)d_out;

    const int N   = in_sizes[0] / 2;   // 32768
    const int nbx = (N + 15) / 16;     // blocks per eval type (16 samples/block)

    // transpose + fp16 weights into ws (bytes 65536..212992)
    pinn_prep<<<dim3(256), dim3(256), 0, stream>>>(W2, W3, wsh);

    pinn_fat<<<dim3(3 * nbx), dim3(128), 0, stream>>>(
        inp, W1, b1, wsh + W2T_HOFF, b2, wsh + W3T_HOFF, b3, W4, b4, ws, N, nbx);
    pinn_reduce<<<dim3(1), dim3(1024), 0, stream>>>(
        ws, out, nbx, 1.0f / (float)N, 0.5f / (float)N);
}

// Round 16
// 164.213 us; speedup vs baseline: 1.0954x; 1.0954x over previous
//
#include <hip/hip_runtime.h>
#include <math.h>

// ---------------------------------------------------------------------------
// PINN beam loss via forward-mode bivariate jets (v16 = v13 + A-prefetch).
// Jet of f(z + t*(1,1) + s*(1,0)):  y[k]=coeff t^k, z[k]=coeff t^k s.
// Layer-1: pre-act = p0 + d*t + wx*s  =>  z[k] = (k+1)*(wx/d)*y[k+1] exactly.
//
// Block = 256 threads (4 waves) = 16 samples. Layer 2 runs as NC separate
// 16x16x32-f16 MFMA GEMMs (one per jet component); D layout (m89):
// col=lane&15=sample, row=(lane>>4)*4+r -> tanh_jet stays lane-local.
// v16 changes vs v13 (which measured 186us steady, MfmaUtil 21/VALUBusy 46,
// ~33% no-issue bubbles):
//  1. A fragments (W2t rows, L2 ~200cyc) prefetched into registers at chunk
//     top, BEFORE jet production -> the ~1600cyc jet VALU block hides the A
//     latency instead of every wave stalling on it right after the barrier.
//  2. __launch_bounds__(256,3): unified VGPR cap ~170 -> 3 waves/SIMD.
// v14 (dbuf) and v15 (2-wave/4-tile) were nulls - reverted.
// ---------------------------------------------------------------------------

typedef _Float16 half8 __attribute__((ext_vector_type(8)));
typedef float f32x4 __attribute__((ext_vector_type(4)));

#define W2T_HOFF 32768     // half-offset of W2t[128][512] in ws (byte 65536)
#define W3T_HOFF 98304     // half-offset of W3t[64][128]  in ws (byte 196608)

__device__ __forceinline__ unsigned int pkrtz(float lo, float hi) {
    return __builtin_bit_cast(unsigned int, __builtin_amdgcn_cvt_pkrtz(lo, hi));
}

__device__ __forceinline__ float fast_tanh(float x) {
    float ax = fabsf(x);
    float e  = __expf(-2.0f * ax);
    float y  = (1.0f - e) * __builtin_amdgcn_rcpf(1.0f + e);
    return copysignf(y, x);
}

template<int NA, int NB>
__device__ __forceinline__ void tanh_jet(const float (&p)[NA], const float (&q)[NB],
                                         float (&y)[NA], float (&r)[NB]) {
    constexpr int NU = ((NA - 1) > NB ? (NA - 1) : NB);
    float u[NU];
    y[0] = fast_tanh(p[0]);
    u[0] = fmaf(-y[0], y[0], 1.0f);
    if constexpr (NA >= 2) y[1] = u[0] * p[1];
    if constexpr (NU >= 2) u[1] = -2.0f * y[0] * y[1];
    if constexpr (NA >= 3) y[2] = fmaf(u[0], p[2], 0.5f * u[1] * p[1]);
    if constexpr (NU >= 3) u[2] = -fmaf(2.0f * y[0], y[2], y[1] * y[1]);
    if constexpr (NA >= 4) y[3] = fmaf(u[0], p[3], fmaf((2.0f/3.0f) * u[1], p[2],
                                       (1.0f/3.0f) * u[2] * p[1]));
    if constexpr (NU >= 4) u[3] = -2.0f * fmaf(y[0], y[3], y[1] * y[2]);
    if constexpr (NA >= 5) y[4] = fmaf(u[0], p[4], fmaf(0.75f * u[1], p[3],
                                       fmaf(0.5f * u[2], p[2], 0.25f * u[3] * p[1])));
    #pragma unroll
    for (int k = 0; k < NB; ++k) {
        float s = 0.0f;
        #pragma unroll
        for (int j = 0; j <= k; ++j) s = fmaf(u[j], q[k - j], s);
        r[k] = s;
    }
}

// layer-1 jet of neuron nn, interleaved [y0,z0,y1,z1,...,y_{NB-1},z_{NB-1},y_{NA-1}]
template<int NA, int NB, int NC>
__device__ __forceinline__ void l1jet(int nn, float x_in, float a_in,
                                      const float* __restrict__ W1,
                                      const float* __restrict__ b1,
                                      float (&jt)[NC]) {
    const float wx = W1[nn];
    const float wa = W1[512 + nn];
    float d = wx + wa;
    if (d == 0.0f) d = 1e-30f;
    const float p0 = fmaf(wx, x_in, fmaf(wa, a_in, b1[nn]));
    const float y0 = fast_tanh(p0);
    const float u0 = fmaf(-y0, y0, 1.0f);
    const float e  = wx * __builtin_amdgcn_rcpf(d);
    float y1 = 0.0f, y2 = 0.0f, y3 = 0.0f, y4 = 0.0f;
    if constexpr (NA >= 2) y1 = u0 * d;
    if constexpr (NA >= 3) { const float u1 = -2.0f * y0 * y1; y2 = 0.5f * u1 * d; }
    if constexpr (NA >= 4) { const float u2 = -fmaf(2.0f * y0, y2, y1 * y1);
                             y3 = (1.0f/3.0f) * u2 * d; }
    if constexpr (NA >= 5) { const float u3 = -2.0f * fmaf(y0, y3, y1 * y2);
                             y4 = 0.25f * u3 * d; }
    jt[0] = y0;
    jt[1] = e * y1;
    if constexpr (NB >= 2) { jt[2] = y1; jt[3] = 2.0f * e * y2; }
    if constexpr (NB >= 3) { jt[4] = y2; jt[5] = 3.0f * e * y3; }
    if constexpr (NB >= 4) { jt[6] = y3; jt[7] = 4.0f * e * y4; }
    if constexpr (NA == 2) jt[2 * NB] = y1;
    else if constexpr (NA == 3) jt[2 * NB] = y2;
    else if constexpr (NA == 4) jt[2 * NB] = y3;
    else                        jt[2 * NB] = y4;
}

// Transpose + fp16-convert the weights: W2t[n][k] = W2[k][n], W3t[n][k] = W3[k][n]
__global__ __launch_bounds__(256)
void pinn_prep(const float* __restrict__ W2, const float* __restrict__ W3,
               _Float16* __restrict__ wsh)
{
    const int i = blockIdx.x * 256 + threadIdx.x;
    if (i < 65536) {
        const int n = i >> 9, k = i & 511;
        wsh[W2T_HOFF + i] = (_Float16)W2[k * 128 + n];
    }
    if (i < 8192) {
        const int n = i >> 7, k = i & 127;
        wsh[W3T_HOFF + i] = (_Float16)W3[k * 64 + n];
    }
}

template<int NA, int NB, int TYPE>
__device__ __forceinline__ void eval_body(
    int bi, const float* __restrict__ inp,
    const float* __restrict__ W1, const float* __restrict__ b1,
    const _Float16* __restrict__ W2t, const float* __restrict__ b2,
    const _Float16* __restrict__ W3t, const float* __restrict__ b3,
    const float* __restrict__ W4, const float* __restrict__ b4,
    float* __restrict__ ws, int N, int nbx,
    _Float16* __restrict__ hbuf, float (*red)[16][9])
{
    constexpr int NC = NA + NB;              // 9 / 7 / 3 jet components

    const int t    = threadIdx.x;            // 0..255
    const int l    = t & 63;
    const int w    = t >> 6;                 // wave 0..3
    const int col  = l & 15;                 // MFMA N-col = sample
    const int rgrp = l >> 4;                 // 0..3
    const int kb   = rgrp * 8;               // fragment k base (contiguous 8)

    // layer-1 production mapping: sample = t&15, k-local base = (t>>4)*4
    const int s1   = t & 15;
    const int klb  = (t >> 4) * 4;
    const int i1   = bi * 16 + s1;
    const int ii   = (i1 < N) ? i1 : (N - 1);
    const float a1 = inp[2 * ii + 1];
    float x1;
    if constexpr (TYPE == 0)      x1 = inp[2 * ii + 0];
    else if constexpr (TYPE == 1) x1 = 0.0f;
    else                          x1 = 1.0f;

    unsigned int* hb32 = reinterpret_cast<unsigned int*>(hbuf);

    // ---------------- layers 1+2 fused: 8 K-chunks of 64 ----------------
    f32x4 acc0[NC], acc1[NC];
    #pragma unroll
    for (int c = 0; c < NC; ++c) { acc0[c] = (f32x4)0.0f; acc1[c] = (f32x4)0.0f; }

    const _Float16* A0b = W2t + ((2 * w) * 16 + col) * 512;
    const _Float16* A1b = W2t + ((2 * w + 1) * 16 + col) * 512;

    for (int ch = 0; ch < 8; ++ch) {
        // ---- A prefetch for this chunk (2 ks x 2 tiles = 16 VGPRs);
        //      the jet-production VALU below hides the ~200cy L2 latency ----
        half8 Ap00, Ap01, Ap10, Ap11;
        {
            const int kg0 = ch * 64 + kb;
            const int kg1 = ch * 64 + 32 + kb;
            Ap00 = *reinterpret_cast<const half8*>(A0b + kg0);
            Ap01 = *reinterpret_cast<const half8*>(A1b + kg0);
            Ap10 = *reinterpret_cast<const half8*>(A0b + kg1);
            Ap11 = *reinterpret_cast<const half8*>(A1b + kg1);
        }

        // ---- layer 1: 4 jets/thread -> packed fp16 pairs into LDS B-layout
        #pragma unroll
        for (int pr = 0; pr < 2; ++pr) {
            float j0[NC], j1[NC];
            l1jet<NA, NB, NC>(ch * 64 + klb + 2 * pr,     x1, a1, W1, b1, j0);
            l1jet<NA, NB, NC>(ch * 64 + klb + 2 * pr + 1, x1, a1, W1, b1, j1);
            #pragma unroll
            for (int c = 0; c < NC; ++c)
                hb32[(c * 16 + s1) * 36 + (klb >> 1) + pr] = pkrtz(j0[c], j1[c]);
        }
        __syncthreads();

        // ---- layer 2: 2 K-steps x NC comps, 2 row-tiles per wave ----
        #pragma unroll
        for (int c = 0; c < NC; ++c) {
            const half8 B0 = *reinterpret_cast<const half8*>(
                hbuf + (c * 16 + col) * 72 + kb);
            acc0[c] = __builtin_amdgcn_mfma_f32_16x16x32_f16(Ap00, B0, acc0[c], 0, 0, 0);
            acc1[c] = __builtin_amdgcn_mfma_f32_16x16x32_f16(Ap01, B0, acc1[c], 0, 0, 0);
            const half8 B1 = *reinterpret_cast<const half8*>(
                hbuf + (c * 16 + col) * 72 + 32 + kb);
            acc0[c] = __builtin_amdgcn_mfma_f32_16x16x32_f16(Ap10, B1, acc0[c], 0, 0, 0);
            acc1[c] = __builtin_amdgcn_mfma_f32_16x16x32_f16(Ap11, B1, acc1[c], 0, 0, 0);
        }
        __syncthreads();
    }

    // ---------------- layer-2 activation (lane-local, in place) ------------
    // lane holds n2 = tile*16 + rgrp*4 + r for tiles {2w, 2w+1}, sample = col.
    {
        const float* b2p0 = b2 + (2 * w) * 16 + rgrp * 4;
        const float* b2p1 = b2 + (2 * w + 1) * 16 + rgrp * 4;
        #pragma unroll
        for (int r = 0; r < 4; ++r) {
            {
                float pj[NA], qj[NB], yj[NA], rj[NB];
                #pragma unroll
                for (int j = 0; j < NA; ++j) pj[j] = acc0[2 * j][r];
                #pragma unroll
                for (int j = 0; j < NB; ++j) qj[j] = acc0[2 * j + 1][r];
                pj[0] += b2p0[r];
                tanh_jet<NA, NB>(pj, qj, yj, rj);
                #pragma unroll
                for (int j = 0; j < NA; ++j) acc0[2 * j][r] = yj[j];
                #pragma unroll
                for (int j = 0; j < NB; ++j) acc0[2 * j + 1][r] = rj[j];
            }
            {
                float pj[NA], qj[NB], yj[NA], rj[NB];
                #pragma unroll
                for (int j = 0; j < NA; ++j) pj[j] = acc1[2 * j][r];
                #pragma unroll
                for (int j = 0; j < NB; ++j) qj[j] = acc1[2 * j + 1][r];
                pj[0] += b2p1[r];
                tanh_jet<NA, NB>(pj, qj, yj, rj);
                #pragma unroll
                for (int j = 0; j < NA; ++j) acc1[2 * j][r] = yj[j];
                #pragma unroll
                for (int j = 0; j < NB; ++j) acc1[2 * j + 1][r] = rj[j];
            }
        }
    }

    // ---------------- layer 3: two store/mfma passes over K=128 ------------
    f32x4 acc3[NC];
    #pragma unroll
    for (int c = 0; c < NC; ++c) acc3[c] = (f32x4)0.0f;
    const _Float16* A3b = W3t + (w * 16 + col) * 128;

    #pragma unroll
    for (int pass = 0; pass < 2; ++pass) {
        // A3 prefetch for this pass (hidden under the store phase + barrier)
        half8 A3p0, A3p1;
        {
            const int kg0 = pass * 64 + kb;
            A3p0 = *reinterpret_cast<const half8*>(A3b + kg0);
            A3p1 = *reinterpret_cast<const half8*>(A3b + kg0 + 32);
        }
        __syncthreads();                     // prior jet-buffer reads complete
        if ((w >> 1) == pass) {              // waves owning rows [64p,64p+64)
            const int base0 = (w & 1) * 32 + rgrp * 4;        // tile 2w
            const int base1 = base0 + 16;                     // tile 2w+1
            #pragma unroll
            for (int c = 0; c < NC; ++c) {
                hb32[(c * 16 + col) * 36 + (base0 >> 1)]     = pkrtz(acc0[c][0], acc0[c][1]);
                hb32[(c * 16 + col) * 36 + (base0 >> 1) + 1] = pkrtz(acc0[c][2], acc0[c][3]);
                hb32[(c * 16 + col) * 36 + (base1 >> 1)]     = pkrtz(acc1[c][0], acc1[c][1]);
                hb32[(c * 16 + col) * 36 + (base1 >> 1) + 1] = pkrtz(acc1[c][2], acc1[c][3]);
            }
        }
        __syncthreads();
        #pragma unroll
        for (int c = 0; c < NC; ++c) {
            const half8 B0 = *reinterpret_cast<const half8*>(
                hbuf + (c * 16 + col) * 72 + kb);
            acc3[c] = __builtin_amdgcn_mfma_f32_16x16x32_f16(A3p0, B0, acc3[c], 0, 0, 0);
            const half8 B1 = *reinterpret_cast<const half8*>(
                hbuf + (c * 16 + col) * 72 + 32 + kb);
            acc3[c] = __builtin_amdgcn_mfma_f32_16x16x32_f16(A3p1, B1, acc3[c], 0, 0, 0);
        }
    }

    // ---------------- layer 4 + loss ----------------
    // lane holds n3 = w*16 + rgrp*4 + r, sample = col.
    float part[NC];
    #pragma unroll
    for (int c = 0; c < NC; ++c) part[c] = 0.0f;
    {
        const float* b3p = b3 + w * 16 + rgrp * 4;
        const float* w4p = W4 + w * 16 + rgrp * 4;
        #pragma unroll
        for (int r = 0; r < 4; ++r) {
            float pj[NA], qj[NB], yj[NA], rj[NB];
            #pragma unroll
            for (int j = 0; j < NA; ++j) pj[j] = acc3[2 * j][r];
            #pragma unroll
            for (int j = 0; j < NB; ++j) qj[j] = acc3[2 * j + 1][r];
            pj[0] += b3p[r];
            tanh_jet<NA, NB>(pj, qj, yj, rj);
            const float w4 = w4p[r];
            #pragma unroll
            for (int c = 0; c < NA; ++c) part[c] = fmaf(w4, yj[c], part[c]);
            #pragma unroll
            for (int c = 0; c < NB; ++c) part[NA + c] = fmaf(w4, rj[c], part[NA + c]);
        }
    }
    // reduce over the 4 row-groups of the wave
    #pragma unroll
    for (int c = 0; c < NC; ++c) {
        part[c] += __shfl_xor(part[c], 16, 64);
        part[c] += __shfl_xor(part[c], 32, 64);
    }
    if (l < 16) {
        #pragma unroll
        for (int c = 0; c < NC; ++c) red[w][l][c] = part[c];
    }
    __syncthreads();

    if (t < 16) {
        float pp[NC];
        #pragma unroll
        for (int c = 0; c < NC; ++c)
            pp[c] = red[0][t][c] + red[1][t][c] + red[2][t][c] + red[3][t][c];
        const int is = bi * 16 + t;
        const bool valid = (is < N);
        const float a_s = inp[2 * ((is < N) ? is : (N - 1)) + 1];
        const float A0v = pp[0] + b4[0];
        float t0 = 0.0f, t1 = 0.0f, t2 = 0.0f;
        constexpr float CC = 1.0f;   // P/(E*I)
        if constexpr (TYPE == 0) {
            const float gx = 6.0f * pp[NA + 3];
            const float ga = 24.0f * pp[4] - gx;
            t0 = (gx + CC) * (gx + CC) + (ga + CC) * (ga + CC);
        }
        if constexpr (TYPE == 1) {
            t0 = A0v * A0v;
            const float gx = pp[NA + 0];
            const float ga = pp[1] - gx;
            t1 = gx * gx + ga * ga;
        }
        if constexpr (TYPE == 2) {
            const float wa = a_s * A0v;
            t0 = wa * wa;
            const float g2x = pp[NA + 1];
            const float g2a = 2.0f * pp[2] - g2x;
            t1 = g2x * g2x + g2a * g2a;
            const float g3x = 2.0f * pp[NA + 2];
            const float g3a = 6.0f * pp[3] - g3x;
            const float om = 1.0f - a_s;
            t2 = om * om * (g3x * g3x + g3a * g3a);
        }
        if (!valid) { t0 = 0.0f; t1 = 0.0f; t2 = 0.0f; }
        #pragma unroll
        for (int m = 1; m <= 8; m <<= 1) {
            t0 += __shfl_xor(t0, m, 64);
            if constexpr (TYPE != 0) t1 += __shfl_xor(t1, m, 64);
            if constexpr (TYPE == 2) t2 += __shfl_xor(t2, m, 64);
        }
        if (t == 0) {
            if constexpr (TYPE == 0) {
                ws[bi] = t0;
            } else if constexpr (TYPE == 1) {
                ws[nbx + bi]     = t0;
                ws[2 * nbx + bi] = t1;
            } else {
                ws[3 * nbx + bi] = t0;
                ws[4 * nbx + bi] = t1;
                ws[5 * nbx + bi] = t2;
            }
        }
    }
}

__global__ __launch_bounds__(256, 3)
void pinn_fat(const float* __restrict__ inp,
              const float* __restrict__ W1, const float* __restrict__ b1,
              const _Float16* __restrict__ W2t, const float* __restrict__ b2,
              const _Float16* __restrict__ W3t, const float* __restrict__ b3,
              const float* __restrict__ W4, const float* __restrict__ b4,
              float* __restrict__ ws, int N, int nbx)
{
    __shared__ __align__(16) _Float16 hbuf[10368];   // [9][16][72] = 20736 B
    __shared__ float red[4][16][9];                  // 2304 B
    const int b = blockIdx.x;
    if (b < nbx)
        eval_body<5, 4, 0>(b, inp, W1, b1, W2t, b2, W3t, b3, W4, b4, ws, N, nbx, hbuf, red);
    else if (b < 2 * nbx)
        eval_body<4, 3, 2>(b - nbx, inp, W1, b1, W2t, b2, W3t, b3, W4, b4, ws, N, nbx, hbuf, red);
    else
        eval_body<2, 1, 1>(b - 2 * nbx, inp, W1, b1, W2t, b2, W3t, b3, W4, b4, ws, N, nbx, hbuf, red);
}

__global__ __launch_bounds__(1024)
void pinn_reduce(const float* __restrict__ ws, float* __restrict__ out,
                 int G, float invN, float inv2N)
{
    __shared__ float sh[16 * 6];
    float s[6];
    #pragma unroll
    for (int q = 0; q < 6; ++q) {
        float acc = 0.0f;
        for (int i = threadIdx.x; i < G; i += 1024) acc += ws[q * G + i];
        #pragma unroll
        for (int m = 1; m <= 32; m <<= 1) acc += __shfl_xor(acc, m, 64);
        s[q] = acc;
    }
    const int wid = threadIdx.x >> 6;
    if ((threadIdx.x & 63) == 0) {
        #pragma unroll
        for (int q = 0; q < 6; ++q) sh[wid * 6 + q] = s[q];
    }
    __syncthreads();
    if (threadIdx.x == 0) {
        float r[6];
        #pragma unroll
        for (int q = 0; q < 6; ++q) {
            float acc = 0.0f;
            for (int w = 0; w < 16; ++w) acc += sh[w * 6 + q];
            r[q] = acc;
        }
        const float pde   = r[0] * inv2N;
        const float w0    = r[1] * invN;
        const float w0x   = r[2] * inv2N;
        const float wL    = r[3] * invN;
        const float wLxx  = r[4] * inv2N;
        const float wLxxx = r[5] * inv2N;
        out[0] = pde + w0 + w0x + wL + wLxx + wLxxx;
        out[1] = pde;
        out[2] = w0;
        out[3] = w0x;
        out[4] = wL;
        out[5] = wLxx;
        out[6] = wLxxx;
    }
}

extern "C" void kernel_launch(void* const* d_in, const int* in_sizes, int n_in,
                              void* d_out, int out_size, void* d_ws, size_t ws_size,
                              hipStream_t stream) {
    const float* inp = (const float*)d_in[0];
    const float* W1  = (const float*)d_in[1];
    const float* b1  = (const float*)d_in[2];
    const float* W2  = (const float*)d_in[3];
    const float* b2  = (const float*)d_in[4];
    const float* W3  = (const float*)d_in[5];
    const float* b3  = (const float*)d_in[6];
    const float* W4  = (const float*)d_in[7];
    const float* b4  = (const float*)d_in[8];
    float* ws  = (float*)d_ws;
    _Float16* wsh = (_Float16*)d_ws;
    float* out = (float*)d_out;

    const int N   = in_sizes[0] / 2;   // 32768
    const int nbx = (N + 15) / 16;     // blocks per eval type (16 samples/block)

    // transpose + fp16 weights into ws (bytes 65536..212992)
    pinn_prep<<<dim3(256), dim3(256), 0, stream>>>(W2, W3, wsh);

    pinn_fat<<<dim3(3 * nbx), dim3(256), 0, stream>>>(
        inp, W1, b1, wsh + W2T_HOFF, b2, wsh + W3T_HOFF, b3, W4, b4, ws, N, nbx);
    pinn_reduce<<<dim3(1), dim3(1024), 0, stream>>>(
        ws, out, nbx, 1.0f / (float)N, 0.5f / (float)N);
}